// Round 15
// baseline (86.262 us; speedup 1.0000x reference)
//
#include <hip/hip_runtime.h>
#include <hip/hip_bf16.h>
#include <stdint.h>

#define MARGIN_C 0.5f
#define POS_MARGIN_C 0.05f
#define EPS_C 1e-6f
#define POS_THR (1.0f - EPS_C - POS_MARGIN_C)
#define XTHR_POS 0.050001f

typedef float f32x4 __attribute__((ext_vector_type(4)));
typedef int i32x4v __attribute__((ext_vector_type(4)));
typedef int i32x8v __attribute__((ext_vector_type(8)));

static __device__ __forceinline__ void gload_lds16(const void* g, void* lds) {
    __builtin_amdgcn_global_load_lds(
        (const __attribute__((address_space(1))) char*)g,
        (__attribute__((address_space(3))) char*)lds,
        16, 0, 0);
}

// ---------------------------------------------------------------------------
// fp4 e2m1 encode, fixed scale 2^-4 (e8m0 = 123 = 0x7B).
// ---------------------------------------------------------------------------
static __device__ __forceinline__ uint32_t nib_fp4(float x) {
    float ax = fabsf(x) * 16.0f;
    uint32_t u = ax < 0.25f ? 0u
               : ax < 0.75f ? 1u
               : ax < 1.25f ? 2u
               : ax < 1.75f ? 3u
               : ax < 2.5f  ? 4u
               : ax < 3.5f  ? 5u
               : ax < 5.0f  ? 6u : 7u;
    return u | (x < 0.0f ? 8u : 0u);
}

__global__ void cvt2_f32_to_fp4(const float* __restrict__ x1, uint32_t* __restrict__ o1, int n1,
                                const float* __restrict__ x2, uint32_t* __restrict__ o2, int n2) {
    int idx = blockIdx.x * blockDim.x + threadIdx.x;
    int stride = gridDim.x * blockDim.x;
    int u1 = n1 >> 5, u2 = n2 >> 5;
    for (int i = idx; i < u1 + u2; i += stride) {
        const float* src = (i < u1) ? (x1 + (size_t)i * 32)
                                    : (x2 + (size_t)(i - u1) * 32);
        uint32_t* dst = (i < u1) ? (o1 + (size_t)i * 4)
                                 : (o2 + (size_t)(i - u1) * 4);
        uint32_t wds[4];
#pragma unroll
        for (int wd = 0; wd < 4; ++wd) {
            float4 a = ((const float4*)src)[2 * wd];
            float4 b = ((const float4*)src)[2 * wd + 1];
            uint32_t v = 0;
            v |= nib_fp4(a.x);
            v |= nib_fp4(a.y) << 4;
            v |= nib_fp4(a.z) << 8;
            v |= nib_fp4(a.w) << 12;
            v |= nib_fp4(b.x) << 16;
            v |= nib_fp4(b.y) << 20;
            v |= nib_fp4(b.z) << 24;
            v |= nib_fp4(b.w) << 28;
            wds[wd] = v;
        }
        uint4 o; o.x = wds[0]; o.y = wds[1]; o.z = wds[2]; o.w = wds[3];
        *(uint4*)dst = o;
    }
}

// ===========================================================================
// Main (R13 K-loop verbatim, 40.6 us proven): 256x128 tile, 512 threads =
// 8 waves (4x2), fp4, MX MFMA 16x16x128, plain 2-barrier single-buffer loop.
// Guarded fast-path epilogue. Fused finalize via last-block election (R14-
// proven correct): relaxed agent-scope partials stores + threadfence + ctr.
// ===========================================================================
__global__ __launch_bounds__(512) void sim_fp4(
    const char* __restrict__ Af4, const char* __restrict__ Bf4,
    const int* __restrict__ L1, const int* __restrict__ L2,
    float* __restrict__ partials, unsigned int* __restrict__ ctr,
    float* __restrict__ out, int N, int M, int D, int nwg) {
    __shared__ __align__(16) char smA[256 * 64];   // 16 KB
    __shared__ __align__(16) char smB[128 * 64];   // 8 KB
    __shared__ int sl1[256];
    __shared__ int sl2[128];
    __shared__ float red3[8][3];
    __shared__ int elect;

    const int tid = threadIdx.x;
    const int lane = tid & 63;
    const int w = tid >> 6;              // 0..7
    const int wR = w >> 1, wC = w & 1;   // 4x2 wave grid
    const int Db = D >> 1;               // bytes per row

    const int nby = M >> 7;
    int wg = blockIdx.x;
    if ((nwg & 7) == 0) wg = (wg & 7) * (nwg >> 3) + (wg >> 3);  // XCD swizzle
    const int bi = wg / nby, bj = wg % nby;
    const int i0 = bi << 8, j0 = bj << 7;

    if (tid < 256) sl1[tid] = L1[i0 + tid];
    else if (tid < 384) sl2[tid - 256] = L2[j0 + tid - 256];

    // hoisted staging pointers (advance by 64 B per K-tile)
    const char* gAp[2];
    int ldsAo[2];
#pragma unroll
    for (int s = 0; s < 2; ++s) {
        int chunk = s * 512 + tid;          // A: 1024 chunks (256 rows x 4)
        int row = chunk >> 2, cpos = chunk & 3;
        int csrc = cpos ^ ((row >> 1) & 3); // involution (rule 21)
        gAp[s] = Af4 + (size_t)(i0 + row) * Db + csrc * 16;
        ldsAo[s] = (s * 512 + (tid & ~63)) * 16;
    }
    const char* gBp;
    int ldsBo;
    {
        int row = tid >> 2, cpos = tid & 3; // B: 512 chunks (128 rows x 4)
        int csrc = cpos ^ ((row >> 1) & 3);
        gBp = Bf4 + (size_t)(j0 + row) * Db + csrc * 16;
        ldsBo = (tid & ~63) * 16;
    }

    // hoisted LDS read offsets (swizzled)
    const int r = lane & 15;
    const int q = lane >> 4;               // k-chunk 0..3 (32 elems = 16 B)
    int offA[4], offB[4];
#pragma unroll
    for (int m = 0; m < 4; ++m) {
        int row = wR * 64 + m * 16 + r;
        offA[m] = row * 64 + ((q ^ ((row >> 1) & 3)) << 4);
    }
#pragma unroll
    for (int n = 0; n < 4; ++n) {
        int row = wC * 64 + n * 16 + r;
        offB[n] = row * 64 + ((q ^ ((row >> 1) & 3)) << 4);
    }

    f32x4 acc[4][4] = {};
    const int kTiles = D >> 7;             // 128 elements per tile
    for (int kt = 0; kt < kTiles; ++kt) {
#pragma unroll
        for (int s = 0; s < 2; ++s) {
            gload_lds16(gAp[s], smA + ldsAo[s]);
            gAp[s] += 64;
        }
        gload_lds16(gBp, smB + ldsBo);
        gBp += 64;
        __syncthreads();

        i32x8v a[4];
#pragma unroll
        for (int m = 0; m < 4; ++m) {
            i32x4v v = *(const i32x4v*)(smA + offA[m]);
            a[m] = __builtin_shufflevector(v, v, 0, 1, 2, 3, -1, -1, -1, -1);
        }
#pragma unroll
        for (int n = 0; n < 4; ++n) {
            i32x4v v = *(const i32x4v*)(smB + offB[n]);
            i32x8v b = __builtin_shufflevector(v, v, 0, 1, 2, 3, -1, -1, -1, -1);
#pragma unroll
            for (int m = 0; m < 4; ++m)
                acc[m][n] = __builtin_amdgcn_mfma_scale_f32_16x16x128_f8f6f4(
                    a[m], b, acc[m][n], 4, 4,            // cbsz=fp4, blgp=fp4
                    0, 0x7B7B7B7B, 0, 0x7B7B7B7B);       // scales = 2^-4
        }
        __syncthreads();
    }

    // ---- guarded fast-path epilogue ----
    float lsum = 0.f;
    int pcn = 0, ncn = 0, fcn = 0;
    const int colc = lane & 15;
    const int rquad = (lane >> 4) * 4;
    int lj_[4];
#pragma unroll
    for (int n = 0; n < 4; ++n) lj_[n] = sl2[wC * 64 + n * 16 + colc];
    int li_[4][4];
#pragma unroll
    for (int m = 0; m < 4; ++m)
#pragma unroll
        for (int v = 0; v < 4; ++v) li_[m][v] = sl1[wR * 64 + m * 16 + rquad + v];

#pragma unroll
    for (int m = 0; m < 4; ++m) {
#pragma unroll
        for (int n = 0; n < 4; ++n) {
            f32x4 a4 = acc[m][n];
            float mx = fmaxf(fmaxf(a4[0], a4[1]), fmaxf(a4[2], a4[3]));
            if (__all(mx < 0.5f)) {
                // no negative hits; every same&valid pair is a positive hit
#pragma unroll
                for (int v = 0; v < 4; ++v) {
                    int li = li_[m][v];
                    bool mk = (li == lj_[n]) && (li > 0);
                    lsum -= mk ? a4[v] : 0.0f;
                    int c = __popcll(__ballot(mk));
                    pcn += c; fcn += c;
                }
            } else {
#pragma unroll
                for (int v = 0; v < 4; ++v) {
                    int li = li_[m][v];
                    bool same = (li == lj_[n]);
                    bool valid = (li > 0);
                    float s = a4[v];
                    float x = same ? 1.0f - s : s;
                    float thr = same ? XTHR_POS : MARGIN_C;
                    bool hit = valid && (x > thr);
                    lsum += hit ? x : 0.0f;
                    pcn += __popcll(__ballot(hit && same));
                    ncn += __popcll(__ballot(hit && !same));
                }
            }
        }
    }
#pragma unroll
    for (int off = 32; off; off >>= 1) lsum += __shfl_down(lsum, off);
    if (lane == 0) {
        red3[w][0] = lsum + (float)fcn;   // Sum(1-s) = fcn - Sum(s) (+ slow terms)
        red3[w][1] = (float)pcn;
        red3[w][2] = (float)ncn;
    }
    __syncthreads();

    // publish partials + elect last block (R14-proven)
    if (tid == 0) {
        float b0 = 0.f, b1 = 0.f, b2 = 0.f;
#pragma unroll
        for (int k = 0; k < 8; ++k) { b0 += red3[k][0]; b1 += red3[k][1]; b2 += red3[k][2]; }
        __hip_atomic_store(&partials[3 * blockIdx.x + 0], b0, __ATOMIC_RELAXED, __HIP_MEMORY_SCOPE_AGENT);
        __hip_atomic_store(&partials[3 * blockIdx.x + 1], b1, __ATOMIC_RELAXED, __HIP_MEMORY_SCOPE_AGENT);
        __hip_atomic_store(&partials[3 * blockIdx.x + 2], b2, __ATOMIC_RELAXED, __HIP_MEMORY_SCOPE_AGENT);
        __threadfence();
        unsigned int prev = atomicAdd(ctr, 1u);
        elect = (prev == (unsigned int)(nwg - 1)) ? 1 : 0;
    }
    __syncthreads();
    if (elect) {
        __threadfence();
        float* redbuf = (float*)smA;   // LDS reuse (post-barrier, compute done)
        float s0 = 0.f, s1 = 0.f, s2 = 0.f;
        for (int i = tid; i < nwg; i += 512) {
            s0 += __hip_atomic_load(&partials[3 * i + 0], __ATOMIC_RELAXED, __HIP_MEMORY_SCOPE_AGENT);
            s1 += __hip_atomic_load(&partials[3 * i + 1], __ATOMIC_RELAXED, __HIP_MEMORY_SCOPE_AGENT);
            s2 += __hip_atomic_load(&partials[3 * i + 2], __ATOMIC_RELAXED, __HIP_MEMORY_SCOPE_AGENT);
        }
        int cnt = 0;
        for (int i = tid; i < N; i += 512) cnt += (L1[i] > 0) ? 1 : 0;
        redbuf[tid * 4 + 0] = s0; redbuf[tid * 4 + 1] = s1;
        redbuf[tid * 4 + 2] = s2; redbuf[tid * 4 + 3] = (float)cnt;
        __syncthreads();
        for (int st = 256; st; st >>= 1) {
            if (tid < st) {
                redbuf[tid * 4 + 0] += redbuf[(tid + st) * 4 + 0];
                redbuf[tid * 4 + 1] += redbuf[(tid + st) * 4 + 1];
                redbuf[tid * 4 + 2] += redbuf[(tid + st) * 4 + 2];
                redbuf[tid * 4 + 3] += redbuf[(tid + st) * 4 + 3];
            }
            __syncthreads();
        }
        if (tid == 0) {
            float n = redbuf[3];
            out[0] = redbuf[0] / n;                        // loss
            out[1] = redbuf[2] / n;                        // avg_neg
            out[2] = rintf(100.f * redbuf[1] / n) * 0.01f; // avg_pos
        }
    }
}

// ---------------------------------------------------------------------------
// Fallback: f32 LDS-tiled 64x64 + separate finalize
// ---------------------------------------------------------------------------
__global__ __launch_bounds__(256) void sim_loss_f32(
    const float* __restrict__ X1, const float* __restrict__ X2,
    const int* __restrict__ L1, const int* __restrict__ L2,
    float* __restrict__ partials, int N, int M, int D) {
    __shared__ float sA[64][33];
    __shared__ float sB[64][33];
    __shared__ int sl1[64], sl2[64];
    __shared__ float red3[4][3];
    const int tid = threadIdx.x;
    const int nby = M >> 6;
    const int bi = blockIdx.x / nby, bj = blockIdx.x % nby;
    const int i0 = bi << 6, j0 = bj << 6;
    if (tid < 64) sl1[tid] = L1[i0 + tid];
    else if (tid < 128) sl2[tid - 64] = L2[j0 + tid - 64];
    const int tx = tid & 15, ty = tid >> 4;
    float acc[4][4] = {};
    for (int k0 = 0; k0 < D; k0 += 32) {
#pragma unroll
        for (int s = 0; s < 8; ++s) {
            int e = s * 256 + tid;
            int row = e >> 5, col = e & 31;
            sA[row][col] = X1[(size_t)(i0 + row) * D + k0 + col];
            sB[row][col] = X2[(size_t)(j0 + row) * D + k0 + col];
        }
        __syncthreads();
#pragma unroll 8
        for (int kk = 0; kk < 32; ++kk) {
            float av[4], bv[4];
#pragma unroll
            for (int p = 0; p < 4; ++p) { av[p] = sA[ty * 4 + p][kk]; bv[p] = sB[tx * 4 + p][kk]; }
#pragma unroll
            for (int p = 0; p < 4; ++p)
#pragma unroll
                for (int qq = 0; qq < 4; ++qq) acc[p][qq] += av[p] * bv[qq];
        }
        __syncthreads();
    }
    float lsum = 0.f; int pcn = 0, ncn = 0;
#pragma unroll
    for (int p = 0; p < 4; ++p) {
        int li = sl1[ty * 4 + p];
#pragma unroll
        for (int qq = 0; qq < 4; ++qq) {
            int lj = sl2[tx * 4 + qq];
            float s = acc[p][qq];
            bool same = (li == lj);
            bool valid = (li > 0);
            float x = same ? 1.0f - s : s;
            float thr = same ? XTHR_POS : MARGIN_C;
            bool hit = valid && (x > thr);
            lsum += hit ? x : 0.0f;
            pcn += __popcll(__ballot(hit && same));
            ncn += __popcll(__ballot(hit && !same));
        }
    }
#pragma unroll
    for (int off = 32; off; off >>= 1) lsum += __shfl_down(lsum, off);
    const int w = tid >> 6;
    if ((tid & 63) == 0) {
        red3[w][0] = lsum; red3[w][1] = (float)pcn; red3[w][2] = (float)ncn;
    }
    __syncthreads();
    if (tid == 0) {
        float4 o = make_float4(0.f, 0.f, 0.f, 0.f);
#pragma unroll
        for (int k = 0; k < 4; ++k) {
            o.x += red3[k][0]; o.y += red3[k][1]; o.z += red3[k][2];
        }
        ((float4*)partials)[blockIdx.x] = o;
    }
}

__global__ void finalize_kernel(const int* __restrict__ L1, int N,
                                const float* __restrict__ partials, int nblocks,
                                float* __restrict__ out) {
    __shared__ float red[256][3];
    __shared__ float redn[256];
    const int tid = threadIdx.x;
    float s0 = 0.f, s1 = 0.f, s2 = 0.f;
    for (int i = tid; i < nblocks; i += 256) {
        float4 p = ((const float4*)partials)[i];
        s0 += p.x; s1 += p.y; s2 += p.z;
    }
    int cnt = 0;
    for (int i = tid; i < N; i += 256) cnt += (L1[i] > 0) ? 1 : 0;
    red[tid][0] = s0; red[tid][1] = s1; red[tid][2] = s2;
    redn[tid] = (float)cnt;
    __syncthreads();
    for (int st = 128; st; st >>= 1) {
        if (tid < st) {
            red[tid][0] += red[tid + st][0];
            red[tid][1] += red[tid + st][1];
            red[tid][2] += red[tid + st][2];
            redn[tid] += redn[tid + st];
        }
        __syncthreads();
    }
    if (tid == 0) {
        float n = redn[0];
        out[0] = red[0][0] / n;
        out[1] = red[0][2] / n;
        out[2] = rintf(100.f * red[0][1] / n) * 0.01f;
    }
}

extern "C" void kernel_launch(void* const* d_in, const int* in_sizes, int n_in,
                              void* d_out, int out_size, void* d_ws, size_t ws_size,
                              hipStream_t stream) {
    const float* x1 = (const float*)d_in[0];
    const int* l1 = (const int*)d_in[1];
    const float* x2 = (const float*)d_in[2];
    const int* l2 = (const int*)d_in[3];
    const int N = in_sizes[1];
    const int M = in_sizes[3];
    const int D = in_sizes[0] / N;
    float* out = (float*)d_out;

    // ws: [partials 3*nwg floats][ctr @61440][Af4 @65536][Bf4]
    const size_t offP = 0;
    const size_t offC = 61440;
    const size_t offA = 65536;
    const size_t offB = offA + ((size_t)N * D >> 1);
    const size_t need = offB + ((size_t)M * D >> 1);
    const int nwgFast = (N >> 8) * (M >> 7);
    const bool fast = (ws_size >= need) && ((N & 255) == 0) && ((M & 127) == 0) &&
                      ((D & 127) == 0) && (nwgFast * 12 <= 61440);

    if (fast) {
        float* partials = (float*)((char*)d_ws + offP);
        unsigned int* ctr = (unsigned int*)((char*)d_ws + offC);
        char* Af4 = (char*)d_ws + offA;
        char* Bf4 = (char*)d_ws + offB;
        hipMemsetAsync(ctr, 0, sizeof(unsigned int), stream);
        cvt2_f32_to_fp4<<<2048, 256, 0, stream>>>(x1, (uint32_t*)Af4, N * D,
                                                  x2, (uint32_t*)Bf4, M * D);
        sim_fp4<<<nwgFast, 512, 0, stream>>>(Af4, Bf4, l1, l2, partials, ctr,
                                             out, N, M, D, nwgFast);
    } else {
        float* partials = (float*)d_ws;
        const int nwg = (N >> 6) * (M >> 6);
        sim_loss_f32<<<nwg, 256, 0, stream>>>(x1, x2, l1, l2, partials, N, M, D);
        finalize_kernel<<<1, 256, 0, stream>>>(l1, N, partials, nwg, out);
    }
}

// Round 16
// 57.387 us; speedup vs baseline: 1.5032x; 1.5032x over previous
//
#include <hip/hip_runtime.h>
#include <hip/hip_bf16.h>
#include <stdint.h>

#define MARGIN_C 0.5f
#define POS_MARGIN_C 0.05f
#define EPS_C 1e-6f
#define POS_THR (1.0f - EPS_C - POS_MARGIN_C)
#define XTHR_POS 0.050001f

typedef float f32x4 __attribute__((ext_vector_type(4)));
typedef int i32x4v __attribute__((ext_vector_type(4)));
typedef int i32x8v __attribute__((ext_vector_type(8)));

static __device__ __forceinline__ void gload_lds16(const void* g, void* lds) {
    __builtin_amdgcn_global_load_lds(
        (const __attribute__((address_space(1))) char*)g,
        (__attribute__((address_space(3))) char*)lds,
        16, 0, 0);
}

// ---------------------------------------------------------------------------
// fp4 e2m1 encode, fixed scale 2^-4 (e8m0 = 123 = 0x7B).
// ---------------------------------------------------------------------------
static __device__ __forceinline__ uint32_t nib_fp4(float x) {
    float ax = fabsf(x) * 16.0f;
    uint32_t u = ax < 0.25f ? 0u
               : ax < 0.75f ? 1u
               : ax < 1.25f ? 2u
               : ax < 1.75f ? 3u
               : ax < 2.5f  ? 4u
               : ax < 3.5f  ? 5u
               : ax < 5.0f  ? 6u : 7u;
    return u | (x < 0.0f ? 8u : 0u);
}

__global__ void cvt2_f32_to_fp4(const float* __restrict__ x1, uint32_t* __restrict__ o1, int n1,
                                const float* __restrict__ x2, uint32_t* __restrict__ o2, int n2) {
    int idx = blockIdx.x * blockDim.x + threadIdx.x;
    int stride = gridDim.x * blockDim.x;
    int u1 = n1 >> 5, u2 = n2 >> 5;
    for (int i = idx; i < u1 + u2; i += stride) {
        const float* src = (i < u1) ? (x1 + (size_t)i * 32)
                                    : (x2 + (size_t)(i - u1) * 32);
        uint32_t* dst = (i < u1) ? (o1 + (size_t)i * 4)
                                 : (o2 + (size_t)(i - u1) * 4);
        uint32_t wds[4];
#pragma unroll
        for (int wd = 0; wd < 4; ++wd) {
            float4 a = ((const float4*)src)[2 * wd];
            float4 b = ((const float4*)src)[2 * wd + 1];
            uint32_t v = 0;
            v |= nib_fp4(a.x);
            v |= nib_fp4(a.y) << 4;
            v |= nib_fp4(a.z) << 8;
            v |= nib_fp4(a.w) << 12;
            v |= nib_fp4(b.x) << 16;
            v |= nib_fp4(b.y) << 20;
            v |= nib_fp4(b.z) << 24;
            v |= nib_fp4(b.w) << 28;
            wds[wd] = v;
        }
        uint4 o; o.x = wds[0]; o.y = wds[1]; o.z = wds[2]; o.w = wds[3];
        *(uint4*)dst = o;
    }
}

// ===========================================================================
// Main (champion config, R13 bench = 40.6 us): 256x128 tile, 512 threads =
// 8 waves (4x2), fp4, MX MFMA 16x16x128 (cbsz/blgp=4), plain 2-barrier
// single-buffer K-loop, guarded fast-path epilogue, SEPARATE finalize
// (per-block device-scope fence proven to cost ~30 us — R14/R15).
// ===========================================================================
__global__ __launch_bounds__(512) void sim_fp4(
    const char* __restrict__ Af4, const char* __restrict__ Bf4,
    const int* __restrict__ L1, const int* __restrict__ L2,
    float* __restrict__ partials, int N, int M, int D) {
    __shared__ __align__(16) char smA[256 * 64];   // 16 KB
    __shared__ __align__(16) char smB[128 * 64];   // 8 KB
    __shared__ int sl1[256];
    __shared__ int sl2[128];
    __shared__ float red3[8][3];

    const int tid = threadIdx.x;
    const int lane = tid & 63;
    const int w = tid >> 6;              // 0..7
    const int wR = w >> 1, wC = w & 1;   // 4x2 wave grid
    const int Db = D >> 1;               // bytes per row

    const int nby = M >> 7;
    const int nwg = (N >> 8) * nby;
    int wg = blockIdx.x;
    if ((nwg & 7) == 0) wg = (wg & 7) * (nwg >> 3) + (wg >> 3);  // XCD swizzle
    const int bi = wg / nby, bj = wg % nby;
    const int i0 = bi << 8, j0 = bj << 7;

    if (tid < 256) sl1[tid] = L1[i0 + tid];
    else if (tid < 384) sl2[tid - 256] = L2[j0 + tid - 256];

    // hoisted staging pointers (advance by 64 B per K-tile)
    const char* gAp[2];
    int ldsAo[2];
#pragma unroll
    for (int s = 0; s < 2; ++s) {
        int chunk = s * 512 + tid;          // A: 1024 chunks (256 rows x 4)
        int row = chunk >> 2, cpos = chunk & 3;
        int csrc = cpos ^ ((row >> 1) & 3); // involution (rule 21)
        gAp[s] = Af4 + (size_t)(i0 + row) * Db + csrc * 16;
        ldsAo[s] = (s * 512 + (tid & ~63)) * 16;
    }
    const char* gBp;
    int ldsBo;
    {
        int row = tid >> 2, cpos = tid & 3; // B: 512 chunks (128 rows x 4)
        int csrc = cpos ^ ((row >> 1) & 3);
        gBp = Bf4 + (size_t)(j0 + row) * Db + csrc * 16;
        ldsBo = (tid & ~63) * 16;
    }

    // hoisted LDS read offsets (swizzled)
    const int r = lane & 15;
    const int q = lane >> 4;               // k-chunk 0..3 (32 elems = 16 B)
    int offA[4], offB[4];
#pragma unroll
    for (int m = 0; m < 4; ++m) {
        int row = wR * 64 + m * 16 + r;
        offA[m] = row * 64 + ((q ^ ((row >> 1) & 3)) << 4);
    }
#pragma unroll
    for (int n = 0; n < 4; ++n) {
        int row = wC * 64 + n * 16 + r;
        offB[n] = row * 64 + ((q ^ ((row >> 1) & 3)) << 4);
    }

    f32x4 acc[4][4] = {};
    const int kTiles = D >> 7;             // 128 elements per tile
    for (int kt = 0; kt < kTiles; ++kt) {
#pragma unroll
        for (int s = 0; s < 2; ++s) {
            gload_lds16(gAp[s], smA + ldsAo[s]);
            gAp[s] += 64;
        }
        gload_lds16(gBp, smB + ldsBo);
        gBp += 64;
        __syncthreads();

        i32x8v a[4];
#pragma unroll
        for (int m = 0; m < 4; ++m) {
            i32x4v v = *(const i32x4v*)(smA + offA[m]);
            a[m] = __builtin_shufflevector(v, v, 0, 1, 2, 3, -1, -1, -1, -1);
        }
#pragma unroll
        for (int n = 0; n < 4; ++n) {
            i32x4v v = *(const i32x4v*)(smB + offB[n]);
            i32x8v b = __builtin_shufflevector(v, v, 0, 1, 2, 3, -1, -1, -1, -1);
#pragma unroll
            for (int m = 0; m < 4; ++m)
                acc[m][n] = __builtin_amdgcn_mfma_scale_f32_16x16x128_f8f6f4(
                    a[m], b, acc[m][n], 4, 4,            // cbsz=fp4, blgp=fp4
                    0, 0x7B7B7B7B, 0, 0x7B7B7B7B);       // scales = 2^-4
        }
        __syncthreads();
    }

    // ---- guarded fast-path epilogue ----
    float lsum = 0.f;              // slow-path x terms MINUS fast-path s terms
    int pcn = 0, ncn = 0, fcn = 0; // wave-uniform (ballot-popcount)
    const int colc = lane & 15;
    const int rquad = (lane >> 4) * 4;
    int lj_[4];
#pragma unroll
    for (int n = 0; n < 4; ++n) lj_[n] = sl2[wC * 64 + n * 16 + colc];
    int li_[4][4];
#pragma unroll
    for (int m = 0; m < 4; ++m)
#pragma unroll
        for (int v = 0; v < 4; ++v) li_[m][v] = sl1[wR * 64 + m * 16 + rquad + v];

#pragma unroll
    for (int m = 0; m < 4; ++m) {
#pragma unroll
        for (int n = 0; n < 4; ++n) {
            f32x4 a4 = acc[m][n];
            float mx = fmaxf(fmaxf(a4[0], a4[1]), fmaxf(a4[2], a4[3]));
            if (__all(mx < 0.5f)) {
                // no negative hits possible; all same&valid are positive hits
#pragma unroll
                for (int v = 0; v < 4; ++v) {
                    int li = li_[m][v];
                    bool mk = (li == lj_[n]) && (li > 0);
                    lsum -= mk ? a4[v] : 0.0f;           // contributes -(s)
                    int c = __popcll(__ballot(mk));
                    pcn += c; fcn += c;                  // contributes +1 each
                }
            } else {
#pragma unroll
                for (int v = 0; v < 4; ++v) {
                    int li = li_[m][v];
                    bool same = (li == lj_[n]);
                    bool valid = (li > 0);
                    float s = a4[v];
                    float x = same ? 1.0f - s : s;
                    float thr = same ? XTHR_POS : MARGIN_C;
                    bool hit = valid && (x > thr);
                    lsum += hit ? x : 0.0f;
                    pcn += __popcll(__ballot(hit && same));
                    ncn += __popcll(__ballot(hit && !same));
                }
            }
        }
    }
#pragma unroll
    for (int off = 32; off; off >>= 1) lsum += __shfl_down(lsum, off);
    if (lane == 0) {
        red3[w][0] = lsum + (float)fcn;   // Sum(1-s) = fcn - Sum(s) (+ slow terms)
        red3[w][1] = (float)pcn;
        red3[w][2] = (float)ncn;
    }
    __syncthreads();
    if (tid == 0) {
        float4 o = make_float4(0.f, 0.f, 0.f, 0.f);
#pragma unroll
        for (int k = 0; k < 8; ++k) {
            o.x += red3[k][0]; o.y += red3[k][1]; o.z += red3[k][2];
        }
        ((float4*)partials)[blockIdx.x] = o;   // (lsum, pcnt, ncnt, 0)
    }
}

// ---------------------------------------------------------------------------
// Fallback: f32 LDS-tiled 64x64 (3-field partials)
// ---------------------------------------------------------------------------
__global__ __launch_bounds__(256) void sim_loss_f32(
    const float* __restrict__ X1, const float* __restrict__ X2,
    const int* __restrict__ L1, const int* __restrict__ L2,
    float* __restrict__ partials, int N, int M, int D) {
    __shared__ float sA[64][33];
    __shared__ float sB[64][33];
    __shared__ int sl1[64], sl2[64];
    __shared__ float red3[4][3];
    const int tid = threadIdx.x;
    const int nby = M >> 6;
    const int bi = blockIdx.x / nby, bj = blockIdx.x % nby;
    const int i0 = bi << 6, j0 = bj << 6;
    if (tid < 64) sl1[tid] = L1[i0 + tid];
    else if (tid < 128) sl2[tid - 64] = L2[j0 + tid - 64];
    const int tx = tid & 15, ty = tid >> 4;
    float acc[4][4] = {};
    for (int k0 = 0; k0 < D; k0 += 32) {
#pragma unroll
        for (int s = 0; s < 8; ++s) {
            int e = s * 256 + tid;
            int row = e >> 5, col = e & 31;
            sA[row][col] = X1[(size_t)(i0 + row) * D + k0 + col];
            sB[row][col] = X2[(size_t)(j0 + row) * D + k0 + col];
        }
        __syncthreads();
#pragma unroll 8
        for (int kk = 0; kk < 32; ++kk) {
            float av[4], bv[4];
#pragma unroll
            for (int p = 0; p < 4; ++p) { av[p] = sA[ty * 4 + p][kk]; bv[p] = sB[tx * 4 + p][kk]; }
#pragma unroll
            for (int p = 0; p < 4; ++p)
#pragma unroll
                for (int qq = 0; qq < 4; ++qq) acc[p][qq] += av[p] * bv[qq];
        }
        __syncthreads();
    }
    float lsum = 0.f; int pcn = 0, ncn = 0;
#pragma unroll
    for (int p = 0; p < 4; ++p) {
        int li = sl1[ty * 4 + p];
#pragma unroll
        for (int qq = 0; qq < 4; ++qq) {
            int lj = sl2[tx * 4 + qq];
            float s = acc[p][qq];
            bool same = (li == lj);
            bool valid = (li > 0);
            float x = same ? 1.0f - s : s;
            float thr = same ? XTHR_POS : MARGIN_C;
            bool hit = valid && (x > thr);
            lsum += hit ? x : 0.0f;
            pcn += __popcll(__ballot(hit && same));
            ncn += __popcll(__ballot(hit && !same));
        }
    }
#pragma unroll
    for (int off = 32; off; off >>= 1) lsum += __shfl_down(lsum, off);
    const int w = tid >> 6;
    if ((tid & 63) == 0) {
        red3[w][0] = lsum; red3[w][1] = (float)pcn; red3[w][2] = (float)ncn;
    }
    __syncthreads();
    if (tid == 0) {
        float4 o = make_float4(0.f, 0.f, 0.f, 0.f);
#pragma unroll
        for (int k = 0; k < 4; ++k) {
            o.x += red3[k][0]; o.y += red3[k][1]; o.z += red3[k][2];
        }
        ((float4*)partials)[blockIdx.x] = o;
    }
}

// ---------------------------------------------------------------------------
// Finalize: partials = (lsum, pcnt, ncnt, 0) per block
// ---------------------------------------------------------------------------
__global__ void finalize_kernel(const int* __restrict__ L1, int N,
                                const float* __restrict__ partials, int nblocks,
                                float* __restrict__ out) {
    __shared__ float red[256][3];
    __shared__ float redn[256];
    const int tid = threadIdx.x;
    float s0 = 0.f, s1 = 0.f, s2 = 0.f;
    for (int i = tid; i < nblocks; i += 256) {
        float4 p = ((const float4*)partials)[i];
        s0 += p.x; s1 += p.y; s2 += p.z;
    }
    int cnt = 0;
    for (int i = tid; i < N; i += 256) cnt += (L1[i] > 0) ? 1 : 0;
    red[tid][0] = s0; red[tid][1] = s1; red[tid][2] = s2;
    redn[tid] = (float)cnt;
    __syncthreads();
    for (int st = 128; st; st >>= 1) {
        if (tid < st) {
            red[tid][0] += red[tid + st][0];
            red[tid][1] += red[tid + st][1];
            red[tid][2] += red[tid + st][2];
            redn[tid] += redn[tid + st];
        }
        __syncthreads();
    }
    if (tid == 0) {
        float n = redn[0];
        out[0] = red[0][0] / n;                        // loss
        out[1] = red[0][2] / n;                        // avg_neg
        out[2] = rintf(100.f * red[0][1] / n) * 0.01f; // avg_pos
    }
}

extern "C" void kernel_launch(void* const* d_in, const int* in_sizes, int n_in,
                              void* d_out, int out_size, void* d_ws, size_t ws_size,
                              hipStream_t stream) {
    const float* x1 = (const float*)d_in[0];
    const int* l1 = (const int*)d_in[1];
    const float* x2 = (const float*)d_in[2];
    const int* l2 = (const int*)d_in[3];
    const int N = in_sizes[1];
    const int M = in_sizes[3];
    const int D = in_sizes[0] / N;
    float* out = (float*)d_out;

    // ws: [partials 64K][Af4 N*D/2][Bf4 M*D/2]
    const size_t offP = 0;
    const size_t offA = 65536;
    const size_t offB = offA + ((size_t)N * D >> 1);
    const size_t need = offB + ((size_t)M * D >> 1);
    const int nwgFast = (N >> 8) * (M >> 7);
    const bool fast = (ws_size >= need) && ((N & 255) == 0) && ((M & 127) == 0) &&
                      ((D & 127) == 0) && (nwgFast * 16 <= 65536);

    if (fast) {
        float* partials = (float*)((char*)d_ws + offP);
        char* Af4 = (char*)d_ws + offA;
        char* Bf4 = (char*)d_ws + offB;
        cvt2_f32_to_fp4<<<2048, 256, 0, stream>>>(x1, (uint32_t*)Af4, N * D,
                                                  x2, (uint32_t*)Bf4, M * D);
        sim_fp4<<<nwgFast, 512, 0, stream>>>(Af4, Bf4, l1, l2, partials, N, M, D);
        finalize_kernel<<<1, 256, 0, stream>>>(l1, N, partials, nwgFast, out);
    } else {
        float* partials = (float*)d_ws;
        const int nwg = (N >> 6) * (M >> 6);
        sim_loss_f32<<<nwg, 256, 0, stream>>>(x1, x2, l1, l2, partials, N, M, D);
        finalize_kernel<<<1, 256, 0, stream>>>(l1, N, partials, nwg, out);
    }
}

// Round 17
// 56.332 us; speedup vs baseline: 1.5313x; 1.0187x over previous
//
#include <hip/hip_runtime.h>
#include <hip/hip_bf16.h>
#include <stdint.h>

#define MARGIN_C 0.5f
#define POS_MARGIN_C 0.05f
#define EPS_C 1e-6f
#define POS_THR (1.0f - EPS_C - POS_MARGIN_C)
#define XTHR_POS 0.050001f

typedef float f32x4 __attribute__((ext_vector_type(4)));
typedef int i32x4v __attribute__((ext_vector_type(4)));
typedef int i32x8v __attribute__((ext_vector_type(8)));

static __device__ __forceinline__ void gload_lds16(const void* g, void* lds) {
    __builtin_amdgcn_global_load_lds(
        (const __attribute__((address_space(1))) char*)g,
        (__attribute__((address_space(3))) char*)lds,
        16, 0, 0);
}

// ---------------------------------------------------------------------------
// fp4 e2m1 encode, fixed scale 2^-4 (e8m0 = 123 = 0x7B).
// ---------------------------------------------------------------------------
static __device__ __forceinline__ uint32_t nib_fp4(float x) {
    float ax = fabsf(x) * 16.0f;
    uint32_t u = ax < 0.25f ? 0u
               : ax < 0.75f ? 1u
               : ax < 1.25f ? 2u
               : ax < 1.75f ? 3u
               : ax < 2.5f  ? 4u
               : ax < 3.5f  ? 5u
               : ax < 5.0f  ? 6u : 7u;
    return u | (x < 0.0f ? 8u : 0u);
}

__global__ void cvt2_f32_to_fp4(const float* __restrict__ x1, uint32_t* __restrict__ o1, int n1,
                                const float* __restrict__ x2, uint32_t* __restrict__ o2, int n2) {
    int idx = blockIdx.x * blockDim.x + threadIdx.x;
    int stride = gridDim.x * blockDim.x;
    int u1 = n1 >> 5, u2 = n2 >> 5;
    for (int i = idx; i < u1 + u2; i += stride) {
        const float* src = (i < u1) ? (x1 + (size_t)i * 32)
                                    : (x2 + (size_t)(i - u1) * 32);
        uint32_t* dst = (i < u1) ? (o1 + (size_t)i * 4)
                                 : (o2 + (size_t)(i - u1) * 4);
        uint32_t wds[4];
#pragma unroll
        for (int wd = 0; wd < 4; ++wd) {
            float4 a = ((const float4*)src)[2 * wd];
            float4 b = ((const float4*)src)[2 * wd + 1];
            uint32_t v = 0;
            v |= nib_fp4(a.x);
            v |= nib_fp4(a.y) << 4;
            v |= nib_fp4(a.z) << 8;
            v |= nib_fp4(a.w) << 12;
            v |= nib_fp4(b.x) << 16;
            v |= nib_fp4(b.y) << 20;
            v |= nib_fp4(b.z) << 24;
            v |= nib_fp4(b.w) << 28;
            wds[wd] = v;
        }
        uint4 o; o.x = wds[0]; o.y = wds[1]; o.z = wds[2]; o.w = wds[3];
        *(uint4*)dst = o;
    }
}

// ===========================================================================
// Main: champion config + paired K-tiles (2 tiles staged per barrier-pair).
// 256x128 tile, 512 threads = 8 waves (4x2), fp4, MX MFMA 16x16x128,
// plain 2-barrier loop over PAIRS of K-tiles (halves the drain count),
// guarded fast-path epilogue, separate finalize.
// ===========================================================================
__global__ __launch_bounds__(512) void sim_fp4(
    const char* __restrict__ Af4, const char* __restrict__ Bf4,
    const int* __restrict__ L1, const int* __restrict__ L2,
    float* __restrict__ partials, int N, int M, int D) {
    __shared__ __align__(16) char smA[2][256 * 64];   // 16 KB x2
    __shared__ __align__(16) char smB[2][128 * 64];   // 8 KB x2
    __shared__ int sl1[256];
    __shared__ int sl2[128];
    __shared__ float red3[8][3];

    const int tid = threadIdx.x;
    const int lane = tid & 63;
    const int w = tid >> 6;              // 0..7
    const int wR = w >> 1, wC = w & 1;   // 4x2 wave grid
    const int Db = D >> 1;               // bytes per row

    const int nby = M >> 7;
    const int nwg = (N >> 8) * nby;
    int wg = blockIdx.x;
    if ((nwg & 7) == 0) wg = (wg & 7) * (nwg >> 3) + (wg >> 3);  // XCD swizzle
    const int bi = wg / nby, bj = wg % nby;
    const int i0 = bi << 8, j0 = bj << 7;

    if (tid < 256) sl1[tid] = L1[i0 + tid];
    else if (tid < 384) sl2[tid - 256] = L2[j0 + tid - 256];

    // hoisted staging pointers (advance by 64 B per K-tile)
    const char* gAp[2];
    int ldsAo[2];
#pragma unroll
    for (int s = 0; s < 2; ++s) {
        int chunk = s * 512 + tid;          // A: 1024 chunks (256 rows x 4)
        int row = chunk >> 2, cpos = chunk & 3;
        int csrc = cpos ^ ((row >> 1) & 3); // involution (rule 21)
        gAp[s] = Af4 + (size_t)(i0 + row) * Db + csrc * 16;
        ldsAo[s] = (s * 512 + (tid & ~63)) * 16;
    }
    const char* gBp;
    int ldsBo;
    {
        int row = tid >> 2, cpos = tid & 3; // B: 512 chunks (128 rows x 4)
        int csrc = cpos ^ ((row >> 1) & 3);
        gBp = Bf4 + (size_t)(j0 + row) * Db + csrc * 16;
        ldsBo = (tid & ~63) * 16;
    }

    auto stage = [&](int buf, int kt) {
#pragma unroll
        for (int s = 0; s < 2; ++s)
            gload_lds16(gAp[s] + kt * 64, smA[buf] + ldsAo[s]);
        gload_lds16(gBp + kt * 64, smB[buf] + ldsBo);
    };

    // hoisted LDS read offsets (swizzled)
    const int r = lane & 15;
    const int q = lane >> 4;               // k-chunk 0..3 (32 elems = 16 B)
    int offA[4], offB[4];
#pragma unroll
    for (int m = 0; m < 4; ++m) {
        int row = wR * 64 + m * 16 + r;
        offA[m] = row * 64 + ((q ^ ((row >> 1) & 3)) << 4);
    }
#pragma unroll
    for (int n = 0; n < 4; ++n) {
        int row = wC * 64 + n * 16 + r;
        offB[n] = row * 64 + ((q ^ ((row >> 1) & 3)) << 4);
    }

    f32x4 acc[4][4] = {};
    auto compute = [&](int buf) {
        i32x8v a[4];
#pragma unroll
        for (int m = 0; m < 4; ++m) {
            i32x4v v = *(const i32x4v*)(smA[buf] + offA[m]);
            a[m] = __builtin_shufflevector(v, v, 0, 1, 2, 3, -1, -1, -1, -1);
        }
#pragma unroll
        for (int n = 0; n < 4; ++n) {
            i32x4v v = *(const i32x4v*)(smB[buf] + offB[n]);
            i32x8v b = __builtin_shufflevector(v, v, 0, 1, 2, 3, -1, -1, -1, -1);
#pragma unroll
            for (int m = 0; m < 4; ++m)
                acc[m][n] = __builtin_amdgcn_mfma_scale_f32_16x16x128_f8f6f4(
                    a[m], b, acc[m][n], 4, 4,            // cbsz=fp4, blgp=fp4
                    0, 0x7B7B7B7B, 0, 0x7B7B7B7B);       // scales = 2^-4
        }
    };

    const int kTiles = D >> 7;             // 128 elements per tile
    int kt = 0;
    for (; kt + 1 < kTiles; kt += 2) {     // paired: one drain per 2 tiles
        stage(0, kt);
        stage(1, kt + 1);
        __syncthreads();
        compute(0);
        compute(1);
        __syncthreads();
    }
    for (; kt < kTiles; ++kt) {            // odd-tail tile (not hit at D=512)
        stage(0, kt);
        __syncthreads();
        compute(0);
        __syncthreads();
    }

    // ---- guarded fast-path epilogue ----
    float lsum = 0.f;              // slow-path x terms MINUS fast-path s terms
    int pcn = 0, ncn = 0, fcn = 0; // wave-uniform (ballot-popcount)
    const int colc = lane & 15;
    const int rquad = (lane >> 4) * 4;
    int lj_[4];
#pragma unroll
    for (int n = 0; n < 4; ++n) lj_[n] = sl2[wC * 64 + n * 16 + colc];
    int li_[4][4];
#pragma unroll
    for (int m = 0; m < 4; ++m)
#pragma unroll
        for (int v = 0; v < 4; ++v) li_[m][v] = sl1[wR * 64 + m * 16 + rquad + v];

#pragma unroll
    for (int m = 0; m < 4; ++m) {
#pragma unroll
        for (int n = 0; n < 4; ++n) {
            f32x4 a4 = acc[m][n];
            float mx = fmaxf(fmaxf(a4[0], a4[1]), fmaxf(a4[2], a4[3]));
            if (__all(mx < 0.5f)) {
                // no negative hits possible; all same&valid are positive hits
#pragma unroll
                for (int v = 0; v < 4; ++v) {
                    int li = li_[m][v];
                    bool mk = (li == lj_[n]) && (li > 0);
                    lsum -= mk ? a4[v] : 0.0f;           // contributes -(s)
                    int c = __popcll(__ballot(mk));
                    pcn += c; fcn += c;                  // contributes +1 each
                }
            } else {
#pragma unroll
                for (int v = 0; v < 4; ++v) {
                    int li = li_[m][v];
                    bool same = (li == lj_[n]);
                    bool valid = (li > 0);
                    float s = a4[v];
                    float x = same ? 1.0f - s : s;
                    float thr = same ? XTHR_POS : MARGIN_C;
                    bool hit = valid && (x > thr);
                    lsum += hit ? x : 0.0f;
                    pcn += __popcll(__ballot(hit && same));
                    ncn += __popcll(__ballot(hit && !same));
                }
            }
        }
    }
#pragma unroll
    for (int off = 32; off; off >>= 1) lsum += __shfl_down(lsum, off);
    if (lane == 0) {
        red3[w][0] = lsum + (float)fcn;   // Sum(1-s) = fcn - Sum(s) (+ slow terms)
        red3[w][1] = (float)pcn;
        red3[w][2] = (float)ncn;
    }
    __syncthreads();
    if (tid == 0) {
        float4 o = make_float4(0.f, 0.f, 0.f, 0.f);
#pragma unroll
        for (int k = 0; k < 8; ++k) {
            o.x += red3[k][0]; o.y += red3[k][1]; o.z += red3[k][2];
        }
        ((float4*)partials)[blockIdx.x] = o;   // (lsum, pcnt, ncnt, 0)
    }
}

// ---------------------------------------------------------------------------
// Fallback: f32 LDS-tiled 64x64 (3-field partials)
// ---------------------------------------------------------------------------
__global__ __launch_bounds__(256) void sim_loss_f32(
    const float* __restrict__ X1, const float* __restrict__ X2,
    const int* __restrict__ L1, const int* __restrict__ L2,
    float* __restrict__ partials, int N, int M, int D) {
    __shared__ float sA[64][33];
    __shared__ float sB[64][33];
    __shared__ int sl1[64], sl2[64];
    __shared__ float red3[4][3];
    const int tid = threadIdx.x;
    const int nby = M >> 6;
    const int bi = blockIdx.x / nby, bj = blockIdx.x % nby;
    const int i0 = bi << 6, j0 = bj << 6;
    if (tid < 64) sl1[tid] = L1[i0 + tid];
    else if (tid < 128) sl2[tid - 64] = L2[j0 + tid - 64];
    const int tx = tid & 15, ty = tid >> 4;
    float acc[4][4] = {};
    for (int k0 = 0; k0 < D; k0 += 32) {
#pragma unroll
        for (int s = 0; s < 8; ++s) {
            int e = s * 256 + tid;
            int row = e >> 5, col = e & 31;
            sA[row][col] = X1[(size_t)(i0 + row) * D + k0 + col];
            sB[row][col] = X2[(size_t)(j0 + row) * D + k0 + col];
        }
        __syncthreads();
#pragma unroll 8
        for (int kk = 0; kk < 32; ++kk) {
            float av[4], bv[4];
#pragma unroll
            for (int p = 0; p < 4; ++p) { av[p] = sA[ty * 4 + p][kk]; bv[p] = sB[tx * 4 + p][kk]; }
#pragma unroll
            for (int p = 0; p < 4; ++p)
#pragma unroll
                for (int qq = 0; qq < 4; ++qq) acc[p][qq] += av[p] * bv[qq];
        }
        __syncthreads();
    }
    float lsum = 0.f; int pcn = 0, ncn = 0;
#pragma unroll
    for (int p = 0; p < 4; ++p) {
        int li = sl1[ty * 4 + p];
#pragma unroll
        for (int qq = 0; qq < 4; ++qq) {
            int lj = sl2[tx * 4 + qq];
            float s = acc[p][qq];
            bool same = (li == lj);
            bool valid = (li > 0);
            float x = same ? 1.0f - s : s;
            float thr = same ? XTHR_POS : MARGIN_C;
            bool hit = valid && (x > thr);
            lsum += hit ? x : 0.0f;
            pcn += __popcll(__ballot(hit && same));
            ncn += __popcll(__ballot(hit && !same));
        }
    }
#pragma unroll
    for (int off = 32; off; off >>= 1) lsum += __shfl_down(lsum, off);
    const int w = tid >> 6;
    if ((tid & 63) == 0) {
        red3[w][0] = lsum; red3[w][1] = (float)pcn; red3[w][2] = (float)ncn;
    }
    __syncthreads();
    if (tid == 0) {
        float4 o = make_float4(0.f, 0.f, 0.f, 0.f);
#pragma unroll
        for (int k = 0; k < 4; ++k) {
            o.x += red3[k][0]; o.y += red3[k][1]; o.z += red3[k][2];
        }
        ((float4*)partials)[blockIdx.x] = o;
    }
}

// ---------------------------------------------------------------------------
// Finalize: partials = (lsum, pcnt, ncnt, 0) per block
// ---------------------------------------------------------------------------
__global__ void finalize_kernel(const int* __restrict__ L1, int N,
                                const float* __restrict__ partials, int nblocks,
                                float* __restrict__ out) {
    __shared__ float red[256][3];
    __shared__ float redn[256];
    const int tid = threadIdx.x;
    float s0 = 0.f, s1 = 0.f, s2 = 0.f;
    for (int i = tid; i < nblocks; i += 256) {
        float4 p = ((const float4*)partials)[i];
        s0 += p.x; s1 += p.y; s2 += p.z;
    }
    int cnt = 0;
    for (int i = tid; i < N; i += 256) cnt += (L1[i] > 0) ? 1 : 0;
    red[tid][0] = s0; red[tid][1] = s1; red[tid][2] = s2;
    redn[tid] = (float)cnt;
    __syncthreads();
    for (int st = 128; st; st >>= 1) {
        if (tid < st) {
            red[tid][0] += red[tid + st][0];
            red[tid][1] += red[tid + st][1];
            red[tid][2] += red[tid + st][2];
            redn[tid] += redn[tid + st];
        }
        __syncthreads();
    }
    if (tid == 0) {
        float n = redn[0];
        out[0] = red[0][0] / n;                        // loss
        out[1] = red[0][2] / n;                        // avg_neg
        out[2] = rintf(100.f * red[0][1] / n) * 0.01f; // avg_pos
    }
}

extern "C" void kernel_launch(void* const* d_in, const int* in_sizes, int n_in,
                              void* d_out, int out_size, void* d_ws, size_t ws_size,
                              hipStream_t stream) {
    const float* x1 = (const float*)d_in[0];
    const int* l1 = (const int*)d_in[1];
    const float* x2 = (const float*)d_in[2];
    const int* l2 = (const int*)d_in[3];
    const int N = in_sizes[1];
    const int M = in_sizes[3];
    const int D = in_sizes[0] / N;
    float* out = (float*)d_out;

    // ws: [partials 64K][Af4 N*D/2][Bf4 M*D/2]
    const size_t offP = 0;
    const size_t offA = 65536;
    const size_t offB = offA + ((size_t)N * D >> 1);
    const size_t need = offB + ((size_t)M * D >> 1);
    const int nwgFast = (N >> 8) * (M >> 7);
    const bool fast = (ws_size >= need) && ((N & 255) == 0) && ((M & 127) == 0) &&
                      ((D & 127) == 0) && (nwgFast * 16 <= 65536);

    if (fast) {
        float* partials = (float*)((char*)d_ws + offP);
        char* Af4 = (char*)d_ws + offA;
        char* Bf4 = (char*)d_ws + offB;
        cvt2_f32_to_fp4<<<2048, 256, 0, stream>>>(x1, (uint32_t*)Af4, N * D,
                                                  x2, (uint32_t*)Bf4, M * D);
        sim_fp4<<<nwgFast, 512, 0, stream>>>(Af4, Bf4, l1, l2, partials, N, M, D);
        finalize_kernel<<<1, 256, 0, stream>>>(l1, N, partials, nwgFast, out);
    } else {
        float* partials = (float*)d_ws;
        const int nwg = (N >> 6) * (M >> 6);
        sim_loss_f32<<<nwg, 256, 0, stream>>>(x1, x2, l1, l2, partials, N, M, D);
        finalize_kernel<<<1, 256, 0, stream>>>(l1, N, partials, nwg, out);
    }
}